// Round 8
// baseline (91.867 us; speedup 1.0000x reference)
//
#include <hip/hip_runtime.h>
#include <hip/hip_bf16.h>

// DiversityLoss: attention_maps [B=64, M=32, H*W=16384] fp32.
// gram[b,i,j] = sum_k (A[b,i,k]^2 * A[b,j,k]^2); loss = mean_b sum_{i<j} relu(0.1-gram)/496.
//
// R6/R7 post-mortem: compiler dissolved both unroll-4 and the rolling prefetch
// buffer (VGPR=40 both), sinking loads to just-before-use -> ~2 loads in flight,
// VALUBusy 1%, latency-bound 120 us. R4 (plain full unroll, same access pattern)
// was ~3x faster -> scheduling, not access pattern, is the limiter.
// R8: FORCE the burst: 32 statically-indexed float4 loads, then
// sched_barrier(0) (nothing may cross) -> all 32 loads in flight per wave,
// ~165 VGPR, 12 waves/CU x 32KB = 384 KB in flight per CU >> BW*latency.
// MFMA trick: for S*S^T, A-frag == B-frag (lane l holds S[l&31][..]); k-layout
// permutations cancel, result symmetric. Tail fused via "last block per batch"
// + __threadfence (agent scope; XCD L2s not cross-coherent), fixed order ->
// deterministic. Precision: gram ~= K/9 ~= 1820 >> 0.1 margin; bf16 sufficient.

#define MARGIN 0.1f

constexpr int B_ = 64;
constexpr int M_ = 32;
constexpr int K_ = 16384;
constexpr int NC = 16;           // k-chunks per batch -> grid 1024
constexpr int KC = K_ / NC;      // 1024 k per block; 256 per wave; 16 MFMA steps

typedef __attribute__((ext_vector_type(8))) short bf16x8;
typedef __attribute__((ext_vector_type(16))) float f32x16;

static __device__ __forceinline__ short f2bf(float f) {
  return __builtin_bit_cast(short, __float2bfloat16(f));
}

// Counters must start at 0 every call (they end at 16/64) -> tiny init dispatch.
__global__ void init_counters(unsigned* __restrict__ cnt) {
  if (threadIdx.x < 65) cnt[threadIdx.x] = 0;
}

__global__ __launch_bounds__(256) void gram_fused(const float* __restrict__ A,
                                                  float* __restrict__ ws_g,
                                                  float* __restrict__ ws_b,
                                                  unsigned* __restrict__ cnt,
                                                  float* __restrict__ out) {
  const int tid  = threadIdx.x;
  const int w    = tid >> 6;       // wave 0..3
  const int lane = tid & 63;
  const int b    = blockIdx.x >> 4;
  const int c    = blockIdx.x & (NC - 1);
  const int row  = lane & 31;      // gram row/col this lane feeds (A and B roles)
  const int kh   = lane >> 5;      // k-half within a 16-k MFMA step

  // lane's stream: row (lane&31), k in [c*KC + w*256, +256), 16 elems/step (2 float4)
  const size_t ebase = (size_t)(b * M_ + row) * K_ + (size_t)c * KC + w * (KC / 4) + (size_t)kh * 8;
  const float4* p = reinterpret_cast<const float4*>(A + ebase);

  // ---- forced 32-load burst: statically indexed, pinned by sched_barrier ----
  float4 f[32];
#pragma unroll
  for (int s = 0; s < 16; ++s) {
    f[2 * s]     = p[s * 4 + 0];
    f[2 * s + 1] = p[s * 4 + 1];
  }
  __builtin_amdgcn_sched_barrier(0);  // loads may not sink below this point

  f32x16 acc = {};
#pragma unroll
  for (int s = 0; s < 16; ++s) {
    const float4 f0 = f[2 * s];
    const float4 f1 = f[2 * s + 1];
    bf16x8 frag;
    frag[0] = f2bf(f0.x * f0.x);
    frag[1] = f2bf(f0.y * f0.y);
    frag[2] = f2bf(f0.z * f0.z);
    frag[3] = f2bf(f0.w * f0.w);
    frag[4] = f2bf(f1.x * f1.x);
    frag[5] = f2bf(f1.y * f1.y);
    frag[6] = f2bf(f1.z * f1.z);
    frag[7] = f2bf(f1.w * f1.w);
    acc = __builtin_amdgcn_mfma_f32_32x32x16_bf16(frag, frag, acc, 0, 0, 0);
  }

  // Cross-wave k-reduce in LDS.
  // C/D layout (HW-verified m74/m101): col = lane&31, row = (r&3) + 8*(r>>2) + 4*(lane>>5)
  __shared__ float red[4][M_ * M_];  // 16 KiB
  __shared__ unsigned flag1, flag2;
#pragma unroll
  for (int r = 0; r < 16; ++r) {
    const int rr = (r & 3) + 8 * (r >> 2) + 4 * kh;
    red[w][rr * 32 + row] = acc[r];
  }
  __syncthreads();

  const float4* R4 = reinterpret_cast<const float4*>(&red[0][0]);
  const float4 s0 = R4[tid], s1 = R4[256 + tid], s2 = R4[512 + tid], s3 = R4[768 + tid];
  float4 o;
  o.x = s0.x + s1.x + s2.x + s3.x;
  o.y = s0.y + s1.y + s2.y + s3.y;
  o.z = s0.z + s1.z + s2.z + s3.z;
  o.w = s0.w + s1.w + s2.w + s3.w;
  reinterpret_cast<float4*>(ws_g)[(size_t)blockIdx.x * 256 + tid] = o;

  // --- fused tail: last block of each batch reduces that batch ---
  __syncthreads();  // all threads' ws_g stores issued before the flag
  if (tid == 0) {
    __threadfence();  // agent-scope release: ws_g visible across XCD L2s
    flag1 = atomicAdd(&cnt[b], 1u);  // device-scope (m20)
  }
  __syncthreads();

  if (flag1 == NC - 1) {  // block-uniform: this block is last for batch b
    if (tid == 0) __threadfence();  // acquire side
    __syncthreads();
    const float4* G4 = reinterpret_cast<const float4*>(ws_g);
    float4 g = make_float4(0.f, 0.f, 0.f, 0.f);
#pragma unroll
    for (int cc = 0; cc < NC; ++cc) {
      const float4 t = G4[((size_t)(b * NC + cc)) * 256 + tid];
      g.x += t.x; g.y += t.y; g.z += t.z; g.w += t.w;
    }
    const float gv[4] = {g.x, g.y, g.z, g.w};
    float local = 0.f;
#pragma unroll
    for (int e = 0; e < 4; ++e) {
      const int idx = tid * 4 + e;
      if ((idx & 31) > (idx >> 5)) local += fmaxf(MARGIN - gv[e], 0.0f);  // strict upper
    }
#pragma unroll
    for (int off = 32; off > 0; off >>= 1) local += __shfl_down(local, off);
    if (lane == 0) red[0][w] = local;
    __syncthreads();

    if (tid == 0) {
      ws_b[b] = (red[0][0] + red[0][1] + red[0][2] + red[0][3]) * (1.0f / 496.0f);
      __threadfence();  // release ws_b
      flag2 = atomicAdd(&cnt[64], 1u);
    }
    __syncthreads();

    if (flag2 == B_ - 1 && w == 0) {  // very last batch: wave 0 does the mean
      if (lane == 0) __threadfence();  // acquire side
      __builtin_amdgcn_wave_barrier();
      float v = ws_b[lane];
#pragma unroll
      for (int off = 32; off > 0; off >>= 1) v += __shfl_down(v, off);
      if (lane == 0) out[0] = v * (1.0f / 64.0f);
    }
  }
}

extern "C" void kernel_launch(void* const* d_in, const int* in_sizes, int n_in,
                              void* d_out, int out_size, void* d_ws, size_t ws_size,
                              hipStream_t stream) {
  const float* A = reinterpret_cast<const float*>(d_in[0]);
  float* out = reinterpret_cast<float*>(d_out);

  // ws: [1024][1024] partial grams (4 MiB) + 64 batch losses + 65 counters
  float* ws_g = reinterpret_cast<float*>(d_ws);
  float* ws_b = ws_g + (size_t)B_ * NC * M_ * M_;
  unsigned* cnt = reinterpret_cast<unsigned*>(ws_b + B_);

  init_counters<<<1, 128, 0, stream>>>(cnt);
  gram_fused<<<B_ * NC, 256, 0, stream>>>(A, ws_g, ws_b, cnt, out);
}